// Round 13
// baseline (1444.522 us; speedup 1.0000x reference)
//
#include <hip/hip_runtime.h>
#include <hip/hip_bf16.h>
#include <hip/hip_cooperative_groups.h>

#define EE 400000
#define NN 50000
#define NCH 8
#define CHUNK (EE / NCH)          // 50000 edges per chunk
#define NTOT (NCH * NN)           // 400000 sort counters
#define SCAN_NBLK ((NTOT + 1023) / 1024)   // 391
#define NTILES (EE / 16)          // 25000
#define TPX (NTILES / 8)          // 3125 tiles per XCD chunk
#define NPTILES ((NN + 15) / 16)
#define INIT_NBLK ((NTOT + 255) / 256)     // 1563
#define MEGA_GRID 1024            // 4 blocks/CU * 256 CU (conservative co-residency)

namespace cg = cooperative_groups;

typedef float f32x4 __attribute__((ext_vector_type(4)));
typedef __bf16 bf16x8 __attribute__((ext_vector_type(8)));
typedef unsigned int u32;
typedef unsigned int u32x4 __attribute__((ext_vector_type(4)));

static __device__ __forceinline__ bf16x8 u4_as_bf8(u32x4 u) {
  return __builtin_bit_cast(bf16x8, u);
}
static __device__ __forceinline__ u32 relu_pk2(u32 d) {
  u32 m = (d & 0x80008000u) >> 15;
  m ^= 0x00010001u;
  return d & ((m << 16) - m);
}
static __device__ __forceinline__ u32 pk2bf(float a, float b) {
  union { __bf16 h[2]; u32 w; } t;
  t.h[0] = (__bf16)a; t.h[1] = (__bf16)b;
  return t.w;
}

// ---------------- fused: pack all B fragments (blocks 0..42) +
//                  zero counters (blocks 43..) + head biases (block 43) -----
__global__ void init_pack_kernel(const float* __restrict__ w10, const float* __restrict__ w11,
                                 const float* __restrict__ w20, const float* __restrict__ w21,
                                 const float* __restrict__ w30, const float* __restrict__ w31,
                                 const float* __restrict__ w40, const float* __restrict__ w41,
                                 const float* __restrict__ wl01, const float* __restrict__ wl1,
                                 const float* __restrict__ wl02, const float* __restrict__ wl2,
                                 const float* __restrict__ bl01, const float* __restrict__ bl02,
                                 const float* __restrict__ bl1, const float* __restrict__ bl2,
                                 __bf16* __restrict__ pk,
                                 int* __restrict__ count, float* __restrict__ headw) {
  const int t = threadIdx.x;
  if (blockIdx.x >= 43) {
    int i = (blockIdx.x - 43) * 256 + t;
    if (i < NTOT) count[i] = 0;
    if (blockIdx.x == 43) {
      if (t < 4) {                      // b_ex[c] = bl01@wl1 + bl1
        float s = bl1[t];
        for (int j = 0; j < 32; ++j) s += bl01[j] * wl1[j * 4 + t];
        headw[160 + t] = s;
      } else if (t == 4) {              // b_p = bl02@wl2 + bl2
        float s = bl2[0];
        for (int j = 0; j < 32; ++j) s += bl02[j] * wl2[j];
        headw[164] = s;
      }
    }
    return;
  }
  const int f = blockIdx.x;
  int stage, lf;
  const float *W0, *W1;
  if (f < 4)       { stage = 1; lf = f;      W0 = w10; W1 = w11; }
  else if (f < 14) { stage = 2; lf = f - 4;  W0 = w20; W1 = w21; }
  else if (f < 28) { stage = 3; lf = f - 14; W0 = w30; W1 = w31; }
  else             { stage = 4; lf = f - 28; W0 = w40; W1 = w41; }
#pragma unroll
  for (int u = 0; u < 2; ++u) {
    int idx = t * 2 + u;
    int lane = idx >> 3, i = idx & 7;
    int l15 = lane & 15, g = lane >> 4;
    int k = 8 * g + i;
    float v = 0.f;
    if (stage == 1) {
      if (lf < 2)      v = (k < 4) ? W0[k * 32 + lf * 16 + l15] : 0.f;
      else             v = W1[k * 32 + (lf - 2) * 16 + l15];
    } else if (stage == 2) {
      if (lf < 4)      { int part = lf >> 1, nb = lf & 1; v = W0[(part * 32 + k) * 32 + nb * 16 + l15]; }
      else if (lf < 6) { int nb = lf - 4; v = (k < 4) ? W0[(64 + k) * 32 + nb * 16 + l15] : 0.f; }
      else if (lf < 8) { int nb = lf - 6; v = W0[(68 + k) * 32 + nb * 16 + l15]; }
      else             { int nb = lf - 8; v = W1[k * 32 + nb * 16 + l15]; }
    } else {
      if (lf < 8)       { int part = lf >> 2, kb = (lf >> 1) & 1, nb = lf & 1;
                          v = W0[(part * 64 + kb * 32 + k) * 32 + nb * 16 + l15]; }
      else if (lf < 12) { int eb = (lf - 8) >> 1, nb = lf & 1;
                          v = W0[(128 + eb * 32 + k) * 32 + nb * 16 + l15]; }
      else if (lf < 14) { int nb = lf - 12; v = W1[k * 32 + nb * 16 + l15]; }
      else {
        if (l15 < 4)      { float s = 0.f; for (int j = 0; j < 32; ++j) s += wl01[k * 32 + j] * wl1[j * 4 + l15]; v = s; }
        else if (l15 == 4){ float s = 0.f; for (int j = 0; j < 32; ++j) s += wl02[k * 32 + j] * wl2[j]; v = s; }
      }
    }
    pk[f * 512 + idx] = (__bf16)v;
  }
}

// ---------------- counting sort, chunk-major (c, r), XCD-local ----------
__global__ void hist_kernel(const int* __restrict__ rowi, int* __restrict__ count) {
  const int c = blockIdx.x & 7;
  const int lb = blockIdx.x >> 3;
  const int nb = gridDim.x >> 3;
  for (int i = lb * blockDim.x + threadIdx.x; i < CHUNK; i += nb * blockDim.x) {
    int e = c * CHUNK + i;
    atomicAdd(&count[c * NN + rowi[e]], 1);
  }
}

__global__ void scanA_kernel(const int* __restrict__ count, int* __restrict__ offs,
                             int* __restrict__ partial) {
  __shared__ int lds[1024];
  const int t = threadIdx.x;
  const int i = blockIdx.x * 1024 + t;
  int v = (i < NTOT) ? count[i] : 0;
  lds[t] = v;
  __syncthreads();
  for (int off = 1; off < 1024; off <<= 1) {
    int u = (t >= off) ? lds[t - off] : 0;
    __syncthreads();
    lds[t] += u;
    __syncthreads();
  }
  int incl = lds[t];
  if (i < NTOT) offs[i] = incl - v;
  if (t == 1023) partial[blockIdx.x] = incl;
}

__global__ void scanB_kernel(const int* __restrict__ partial, int* __restrict__ offs,
                             int* __restrict__ cursor) {
  __shared__ int sbase;
  const int t = threadIdx.x;
  const int b = blockIdx.x;
  if (t < 64) {
    int s = 0;
    for (int j = t; j < b; j += 64) s += partial[j];
#pragma unroll
    for (int o = 32; o > 0; o >>= 1) s += __shfl_down(s, o);
    if (t == 0) sbase = s;
  }
  __syncthreads();
  const int base = sbase;
  const int i = b * 1024 + t;
  if (i < NTOT) {
    int o = offs[i] + base;
    offs[i] = o;
    cursor[i] = o;
  }
  if (b == 0 && t == 0) offs[NTOT] = EE;
}

// scatter: ONE 16B record per edge into its sorted position (XCD-local region)
__global__ void scatter_kernel(const int* __restrict__ rowi, const int* __restrict__ coli,
                               const float* __restrict__ eattr, int* __restrict__ cursor,
                               uint4* __restrict__ record, int* __restrict__ inv) {
  const int c = blockIdx.x & 7;
  const int lb = blockIdx.x >> 3;
  const int nb = gridDim.x >> 3;
  for (int i = lb * blockDim.x + threadIdx.x; i < CHUNK; i += nb * blockDim.x) {
    int e = c * CHUNK + i;
    int r = rowi[e];
    int p = atomicAdd(&cursor[c * NN + r], 1);
    inv[e] = p;
    const float4 v = *(const float4*)(eattr + (size_t)e * 4);
    uint4 rec;
    rec.x = (u32)r;
    rec.y = (u32)coli[e];
    rec.z = pk2bf(v.x, v.y);
    rec.w = pk2bf(v.z, v.w);
    record[p] = rec;
  }
}

// =================== shared device phases ==================================

// segment mean: one WAVE per node, chunk-split halves (grid-stride)
static __device__ void agg_phase(const __bf16* __restrict__ esrc,
                                 const int* __restrict__ offs,
                                 __bf16* __restrict__ dst1, int s1, int o1,
                                 __bf16* __restrict__ dst2, int s2, int o2) {
  const int stride = gridDim.x * blockDim.x;
  for (int idx = blockIdx.x * blockDim.x + threadIdx.x; idx < NN * 64; idx += stride) {
    int n = idx >> 6;
    int half = (idx >> 5) & 1;
    int j = idx & 31;
    float s = 0.f;
    int cnt = 0;
#pragma unroll
    for (int cc = 0; cc < 4; ++cc) {
      int c = half * 4 + cc;
      int a = offs[c * NN + n], b = offs[c * NN + n + 1];
      cnt += b - a;
      for (int t = a; t < b; ++t)
        s += (float)esrc[(size_t)t * 32 + j];
    }
    s += __shfl_xor(s, 32);
    cnt += __shfl_xor(cnt, 32);
    float mean = s / fmaxf((float)cnt, 1.f);
    __bf16 x = (__bf16)fmaxf(mean, 0.f);
    if (half == 0) dst1[(size_t)n * s1 + o1 + j] = x;
    else if (dst2) dst2[(size_t)n * s2 + o2 + j] = x;
  }
}

// node projection: ur[n] = W_r.x[n], uc[n] = W_c.x[n]
template <int NPK>
static __device__ void nodeproj_phase(const __bf16* __restrict__ pk,
                                      const __bf16* __restrict__ xcat, int xoff, int xstride,
                                      __bf16* __restrict__ ur, __bf16* __restrict__ uc) {
  constexpr int NKB = NPK / 32;
  const int tid = threadIdx.x;
  const int lane = tid & 63;
  const int wid = tid >> 6;
  const int l15 = lane & 15;
  const int g = lane >> 4;

  bf16x8 Br[NKB][2], Bc[NKB][2];
#pragma unroll
  for (int kb = 0; kb < NKB; ++kb)
#pragma unroll
    for (int nb = 0; nb < 2; ++nb) {
      Br[kb][nb] = *(const bf16x8*)(pk + (size_t)((0 * NKB + kb) * 2 + nb) * 512 + lane * 8);
      Bc[kb][nb] = *(const bf16x8*)(pk + (size_t)((1 * NKB + kb) * 2 + nb) * 512 + lane * 8);
    }

  for (int t = blockIdx.x * 4 + wid; t < NPTILES; t += gridDim.x * 4) {
    const int base = t * 16;
    const int n = base + l15;
    const int nc = (n < NN) ? n : (NN - 1);

    f32x4 r0 = {0,0,0,0}, r1 = {0,0,0,0}, c0 = {0,0,0,0}, c1 = {0,0,0,0};
#pragma unroll
    for (int kb = 0; kb < NKB; ++kb) {
      bf16x8 a = *(const bf16x8*)(xcat + (size_t)nc * xstride + xoff + kb * 32 + 8 * g);
      r0 = __builtin_amdgcn_mfma_f32_16x16x32_bf16(a, Br[kb][0], r0, 0, 0, 0);
      r1 = __builtin_amdgcn_mfma_f32_16x16x32_bf16(a, Br[kb][1], r1, 0, 0, 0);
      c0 = __builtin_amdgcn_mfma_f32_16x16x32_bf16(a, Bc[kb][0], c0, 0, 0, 0);
      c1 = __builtin_amdgcn_mfma_f32_16x16x32_bf16(a, Bc[kb][1], c1, 0, 0, 0);
    }
#pragma unroll
    for (int r = 0; r < 4; ++r) {
      int m = 4 * g + r;
      if (base + m < NN) {
        size_t row = (size_t)(base + m) * 32;
        ur[row + l15]      = (__bf16)r0[r];
        ur[row + 16 + l15] = (__bf16)r1[r];
        uc[row + l15]      = (__bf16)c0[r];
        uc[row + 16 + l15] = (__bf16)c1[r];
      }
    }
  }
}

// fused edge-conv (MFMA), sorted order, XCD-chunked (R10 body, no prefetch)
template <int STAGE>
static __device__ void conv_phase(float* __restrict__ ldsH,
                                  const __bf16* __restrict__ pk,
                                  const float* __restrict__ B0, const float* __restrict__ B1v,
                                  const uint4* __restrict__ record,
                                  const __bf16* __restrict__ ur,
                                  const __bf16* __restrict__ uc,
                                  const __bf16* __restrict__ ein1,
                                  const __bf16* __restrict__ ein2,
                                  __bf16* __restrict__ d1,
                                  const float* __restrict__ headw,
                                  float* __restrict__ tmpP, float* __restrict__ tmpEX) {
  constexpr int NEB  = (STAGE == 1) ? 1 : 2;
  constexpr int FEB  = (STAGE == 1) ? 0 : (STAGE == 2) ? 4 : 8;
  constexpr int FW1  = (STAGE == 1) ? 2 : (STAGE == 2) ? 8 : 12;

  const int tid = threadIdx.x;
  const int lane = tid & 63;
  const int wid = tid >> 6;
  const int l15 = lane & 15;
  const int g = lane >> 4;

  bf16x8 Bf[NEB][2];
#pragma unroll
  for (int eb = 0; eb < NEB; ++eb)
#pragma unroll
    for (int nb = 0; nb < 2; ++nb)
      Bf[eb][nb] = *(const bf16x8*)(pk + (size_t)(FEB + eb * 2 + nb) * 512 + lane * 8);
  bf16x8 B2f[2];
#pragma unroll
  for (int nb = 0; nb < 2; ++nb)
    B2f[nb] = *(const bf16x8*)(pk + (size_t)(FW1 + nb) * 512 + lane * 8);

  bf16x8 I0, I1;
#pragma unroll
  for (int i = 0; i < 8; ++i) {
    int k = 8 * g + i;
    I0[i] = (k == l15)      ? (__bf16)1.0f : (__bf16)0.0f;
    I1[i] = (k == 16 + l15) ? (__bf16)1.0f : (__bf16)0.0f;
  }

  const float b0j0 = B0[l15], b0j1 = B0[l15 + 16];
  const float b1j0 = B1v[l15], b1j1 = B1v[l15 + 16];

  bf16x8 Bh;
  float bexc = 0.f, bp = 0.f;
  if (STAGE == 4) {
    Bh = *(const bf16x8*)(pk + (size_t)14 * 512 + lane * 8);
    if (l15 < 4) bexc = headw[160 + l15];
    bp = headw[164];
  }

  float* hl = &ldsH[wid * 576];

  const int xcd = blockIdx.x & 7;
  const int wloc = (blockIdx.x >> 3) * 4 + wid;
  const int nwl = (gridDim.x >> 3) * 4;
  for (int t0 = wloc; t0 < TPX; t0 += nwl) {
    const int t = xcd * TPX + t0;
    const int base = t * 16;
    const int p = base + l15;

    const uint4 rec = record[p];

    bf16x8 urf, ucf;
    if (STAGE >= 2) {
      int rid = (int)rec.x, cid = (int)rec.y;
      urf = *(const bf16x8*)(ur + (size_t)rid * 32 + 8 * g);
      ucf = *(const bf16x8*)(uc + (size_t)cid * 32 + 8 * g);
    }

    bf16x8 ae;
    if (STAGE <= 2) {
      u32x4 u = {0, 0, 0, 0};
      if (g == 0) { u.x = rec.z; u.y = rec.w; }
      ae = u4_as_bf8(u);
    }

    f32x4 a0a = {0,0,0,0}, a0b = {0,0,0,0}, a1a = {0,0,0,0}, a1b = {0,0,0,0};
    if (STAGE >= 2) {
      a0a = __builtin_amdgcn_mfma_f32_16x16x32_bf16(urf, I0, a0a, 0, 0, 0);
      a1a = __builtin_amdgcn_mfma_f32_16x16x32_bf16(urf, I1, a1a, 0, 0, 0);
      a0a = __builtin_amdgcn_mfma_f32_16x16x32_bf16(ucf, I0, a0a, 0, 0, 0);
      a1a = __builtin_amdgcn_mfma_f32_16x16x32_bf16(ucf, I1, a1a, 0, 0, 0);
    }
#pragma unroll
    for (int eb = 0; eb < NEB; ++eb) {
      bf16x8 a;
      if (STAGE == 1) {
        a = ae;
      } else if (STAGE == 2) {
        if (eb == 0) a = ae;
        else {
          u32x4 u = *(const u32x4*)(ein1 + (size_t)p * 32 + 8 * g);
          u.x = relu_pk2(u.x); u.y = relu_pk2(u.y); u.z = relu_pk2(u.z); u.w = relu_pk2(u.w);
          a = u4_as_bf8(u);
        }
      } else {
        const __bf16* src = (eb == 0) ? ein1 : ein2;
        u32x4 u = *(const u32x4*)(src + (size_t)p * 32 + 8 * g);
        u.x = relu_pk2(u.x); u.y = relu_pk2(u.y); u.z = relu_pk2(u.z); u.w = relu_pk2(u.w);
        a = u4_as_bf8(u);
      }
      a0b = __builtin_amdgcn_mfma_f32_16x16x32_bf16(a, Bf[eb][0], a0b, 0, 0, 0);
      a1b = __builtin_amdgcn_mfma_f32_16x16x32_bf16(a, Bf[eb][1], a1b, 0, 0, 0);
    }
    f32x4 acc0 = a0a + a0b, acc1 = a1a + a1b;

#pragma unroll
    for (int r = 0; r < 4; ++r) {
      int m = 4 * g + r;
      hl[m * 36 + l15]      = fmaxf(acc0[r] + b0j0, 0.f);
      hl[m * 36 + l15 + 16] = fmaxf(acc1[r] + b0j1, 0.f);
    }
    f32x4 h0 = *(const f32x4*)&hl[l15 * 36 + 8 * g];
    f32x4 h1 = *(const f32x4*)&hl[l15 * 36 + 8 * g + 4];
    bf16x8 a2;
#pragma unroll
    for (int i = 0; i < 4; ++i) { a2[i] = (__bf16)h0[i]; a2[i + 4] = (__bf16)h1[i]; }
    f32x4 o0 = {0,0,0,0}, o1 = {0,0,0,0};
    o0 = __builtin_amdgcn_mfma_f32_16x16x32_bf16(a2, B2f[0], o0, 0, 0, 0);
    o1 = __builtin_amdgcn_mfma_f32_16x16x32_bf16(a2, B2f[1], o1, 0, 0, 0);

    if (STAGE <= 3) {
#pragma unroll
      for (int r = 0; r < 4; ++r) {
        int m = 4 * g + r;
        size_t eo = (size_t)(base + m) * 32;
        d1[eo + l15]      = (__bf16)(o0[r] + b1j0);
        d1[eo + l15 + 16] = (__bf16)(o1[r] + b1j1);
      }
    } else {
#pragma unroll
      for (int r = 0; r < 4; ++r) {
        int m = 4 * g + r;
        hl[m * 36 + l15]      = fmaxf(o0[r] + b1j0, 0.f);
        hl[m * 36 + l15 + 16] = fmaxf(o1[r] + b1j1, 0.f);
      }
      f32x4 q0 = *(const f32x4*)&hl[l15 * 36 + 8 * g];
      f32x4 q1 = *(const f32x4*)&hl[l15 * 36 + 8 * g + 4];
      bf16x8 a3;
#pragma unroll
      for (int i = 0; i < 4; ++i) { a3[i] = (__bf16)q0[i]; a3[i + 4] = (__bf16)q1[i]; }
      f32x4 ho = {0,0,0,0};
      ho = __builtin_amdgcn_mfma_f32_16x16x32_bf16(a3, Bh, ho, 0, 0, 0);
#pragma unroll
      for (int r = 0; r < 4; ++r) {
        int m = 4 * g + r;
        int po = base + m;
        float s = ho[r];
        u32 zz = __shfl(rec.z, m);
        u32 ww = __shfl(rec.w, m);
        float v = 0.f, sq = 0.f;
        if (l15 < 4) {
          u32 wzw = (l15 & 2) ? ww : zz;
          u32 bits = (l15 & 1) ? (wzw & 0xffff0000u) : (wzw << 16);
          v = s + bexc + __uint_as_float(bits);
          sq = v * v;
        }
        sq += __shfl_xor(sq, 1);
        sq += __shfl_xor(sq, 2);
        if (l15 < 4) tmpEX[(size_t)po * 4 + l15] = v * (1.f / fmaxf(sqrtf(sq), 1e-12f));
        if (l15 == 4) tmpP[po] = 1.f / (1.f + __expf(-(s + bp)));
      }
    }
  }
}

static __device__ void unpermute_phase(const int* __restrict__ inv,
                                       const float* __restrict__ tmpP,
                                       const float* __restrict__ tmpEX,
                                       const float* __restrict__ beta,
                                       float* __restrict__ outP, float* __restrict__ outEX,
                                       float* __restrict__ outB) {
  const int stride = gridDim.x * blockDim.x;
  for (int e = blockIdx.x * blockDim.x + threadIdx.x; e < EE; e += stride) {
    int p = inv[e];
    outP[e] = tmpP[p];
    float4 ex = *(const float4*)(tmpEX + (size_t)p * 4);
    *(float4*)(outEX + (size_t)e * 4) = ex;
    if (e < NN * 3) outB[e] = beta[e];
  }
}

struct MegaArgs {
  const __bf16 *pk1, *pk2, *pk3, *pk4;
  const float *b10, *b11, *b20, *b21, *b30, *b31, *b40, *b41;
  const uint4* record;
  const int* offs;
  const int* inv;
  const float* beta;
  __bf16 *e1b, *e2b, *e3b, *ur, *uc, *x21, *x32;
  const float* headw;
  float *tmpP, *tmpEX, *outP, *outEX, *outB;
};

// one cooperative kernel for conv1..unpermute: 11 phases, 10 grid syncs.
__launch_bounds__(256, 4)
__global__ void mega_kernel(MegaArgs a) {
  __shared__ __align__(16) float ldsH[4 * 16 * 36];
  cg::grid_group grid = cg::this_grid();

  conv_phase<1>(ldsH, a.pk1, a.b10, a.b11, a.record, nullptr, nullptr,
                nullptr, nullptr, a.e1b, nullptr, nullptr, nullptr);
  grid.sync();
  agg_phase(a.e1b, a.offs, a.x21, 64, 32, nullptr, 0, 0);
  grid.sync();
  nodeproj_phase<32>(a.pk2, a.x21, 32, 64, a.ur, a.uc);
  grid.sync();
  conv_phase<2>(ldsH, a.pk2, a.b20, a.b21, a.record, a.ur, a.uc,
                a.e1b, nullptr, a.e2b, nullptr, nullptr, nullptr);
  grid.sync();
  agg_phase(a.e2b, a.offs, a.x21, 64, 0, a.x32, 64, 32);
  grid.sync();
  nodeproj_phase<64>(a.pk3, a.x21, 0, 64, a.ur, a.uc);
  grid.sync();
  conv_phase<3>(ldsH, a.pk3, a.b30, a.b31, a.record, a.ur, a.uc,
                a.e2b, a.e1b, a.e3b, nullptr, nullptr, nullptr);
  grid.sync();
  agg_phase(a.e3b, a.offs, a.x32, 64, 0, nullptr, 0, 0);
  grid.sync();
  nodeproj_phase<64>(a.pk4, a.x32, 0, 64, a.ur, a.uc);
  grid.sync();
  conv_phase<4>(ldsH, a.pk4, a.b40, a.b41, a.record, a.ur, a.uc,
                a.e3b, a.e2b, nullptr, a.headw, a.tmpP, a.tmpEX);
  grid.sync();
  unpermute_phase(a.inv, a.tmpP, a.tmpEX, a.beta, a.outP, a.outEX, a.outB);
}

// ---------------- fallback __global__ wrappers (R10 path) ------------------
template <int STAGE>
__launch_bounds__(256, 5)
__global__ void conv_kernel(const __bf16* __restrict__ pk,
                            const float* __restrict__ B0, const float* __restrict__ B1v,
                            const uint4* __restrict__ record,
                            const __bf16* __restrict__ ur, const __bf16* __restrict__ uc,
                            const __bf16* __restrict__ ein1, const __bf16* __restrict__ ein2,
                            __bf16* __restrict__ d1,
                            const float* __restrict__ headw,
                            float* __restrict__ tmpP, float* __restrict__ tmpEX) {
  __shared__ __align__(16) float ldsH[4 * 16 * 36];
  conv_phase<STAGE>(ldsH, pk, B0, B1v, record, ur, uc, ein1, ein2, d1, headw, tmpP, tmpEX);
}

__global__ void agg_kernel(const __bf16* __restrict__ esrc, const int* __restrict__ offs,
                           __bf16* __restrict__ dst1, int s1, int o1,
                           __bf16* __restrict__ dst2, int s2, int o2) {
  agg_phase(esrc, offs, dst1, s1, o1, dst2, s2, o2);
}

template <int NPK>
__launch_bounds__(256, 4)
__global__ void nodeproj_kernel(const __bf16* __restrict__ pk,
                                const __bf16* __restrict__ xcat, int xoff, int xstride,
                                __bf16* __restrict__ ur, __bf16* __restrict__ uc) {
  nodeproj_phase<NPK>(pk, xcat, xoff, xstride, ur, uc);
}

__global__ void unpermute_kernel(const int* __restrict__ inv,
                                 const float* __restrict__ tmpP,
                                 const float* __restrict__ tmpEX,
                                 const float* __restrict__ beta,
                                 float* __restrict__ outP, float* __restrict__ outEX,
                                 float* __restrict__ outB) {
  unpermute_phase(inv, tmpP, tmpEX, beta, outP, outEX, outB);
}

extern "C" void kernel_launch(void* const* d_in, const int* in_sizes, int n_in,
                              void* d_out, int out_size, void* d_ws, size_t ws_size,
                              hipStream_t stream) {
  const float* eattr = (const float*)d_in[2];
  const float* beta = (const float*)d_in[3];
  const float* w10 = (const float*)d_in[4];  const float* b10 = (const float*)d_in[5];
  const float* w11 = (const float*)d_in[6];  const float* b11 = (const float*)d_in[7];
  const float* w20 = (const float*)d_in[8];  const float* b20 = (const float*)d_in[9];
  const float* w21 = (const float*)d_in[10]; const float* b21 = (const float*)d_in[11];
  const float* w30 = (const float*)d_in[12]; const float* b30 = (const float*)d_in[13];
  const float* w31 = (const float*)d_in[14]; const float* b31 = (const float*)d_in[15];
  const float* w40 = (const float*)d_in[16]; const float* b40 = (const float*)d_in[17];
  const float* w41 = (const float*)d_in[18]; const float* b41 = (const float*)d_in[19];
  const float* wl01 = (const float*)d_in[20]; const float* bl01 = (const float*)d_in[21];
  const float* wl02 = (const float*)d_in[22]; const float* bl02 = (const float*)d_in[23];
  const float* wl1 = (const float*)d_in[24];  const float* bl1 = (const float*)d_in[25];
  const float* wl2 = (const float*)d_in[26];  const float* bl2 = (const float*)d_in[27];
  const int* rowi = (const int*)d_in[1];
  const int* coli = rowi + EE;

  char* w = (char*)d_ws;
  auto alloc = [&](size_t bytes) {
    char* p = w;
    w += (bytes + 255) & ~(size_t)255;
    return p;
  };
  __bf16* e1b = (__bf16*)alloc((size_t)EE * 32 * 2);  // pre-relu, sorted order
  __bf16* e2b = (__bf16*)alloc((size_t)EE * 32 * 2);
  __bf16* e3b = (__bf16*)alloc((size_t)EE * 32 * 2);
  __bf16* ur  = (__bf16*)alloc((size_t)NN * 32 * 2);  // node proj, row part
  __bf16* uc  = (__bf16*)alloc((size_t)NN * 32 * 2);  // node proj, col part
  __bf16* x21 = (__bf16*)alloc((size_t)NN * 64 * 2);  // [x2 | x1]
  __bf16* x32 = (__bf16*)alloc((size_t)NN * 64 * 2);  // [x3 | x2]
  int* count = (int*)alloc(NTOT * 4);
  int* offs = (int*)alloc((NTOT + 1) * 4);
  int* cursor = (int*)alloc(NTOT * 4);
  int* inv = (int*)alloc(EE * 4);
  uint4* record = (uint4*)alloc((size_t)EE * 16);     // {rid, cid, ea bf16x4}
  float* tmpP = (float*)alloc((size_t)EE * 4);
  float* tmpEX = (float*)alloc((size_t)EE * 4 * 4);
  float* headw = (float*)alloc(256 * 4);
  int* partial = (int*)alloc(512 * 4);
  __bf16* packw = (__bf16*)alloc((size_t)43 * 512 * 2);

  float* outP = (float*)d_out;
  float* outEX = outP + EE;
  float* outB = outP + (size_t)5 * EE;

  __bf16* pk1 = packw;
  __bf16* pk2 = packw + 4 * 512;
  __bf16* pk3 = packw + 14 * 512;
  __bf16* pk4 = packw + 28 * 512;

  init_pack_kernel<<<43 + INIT_NBLK, 256, 0, stream>>>(
      w10, w11, w20, w21, w30, w31, w40, w41, wl01, wl1, wl02, wl2,
      bl01, bl02, bl1, bl2, packw, count, headw);
  hist_kernel<<<1024, 256, 0, stream>>>(rowi, count);
  scanA_kernel<<<SCAN_NBLK, 1024, 0, stream>>>(count, offs, partial);
  scanB_kernel<<<SCAN_NBLK, 1024, 0, stream>>>(partial, offs, cursor);
  scatter_kernel<<<1024, 256, 0, stream>>>(rowi, coli, eattr, cursor, record, inv);

  MegaArgs ma;
  ma.pk1 = pk1; ma.pk2 = pk2; ma.pk3 = pk3; ma.pk4 = pk4;
  ma.b10 = b10; ma.b11 = b11; ma.b20 = b20; ma.b21 = b21;
  ma.b30 = b30; ma.b31 = b31; ma.b40 = b40; ma.b41 = b41;
  ma.record = record; ma.offs = offs; ma.inv = inv; ma.beta = beta;
  ma.e1b = e1b; ma.e2b = e2b; ma.e3b = e3b; ma.ur = ur; ma.uc = uc;
  ma.x21 = x21; ma.x32 = x32; ma.headw = headw;
  ma.tmpP = tmpP; ma.tmpEX = tmpEX; ma.outP = outP; ma.outEX = outEX; ma.outB = outB;

  void* args[] = { &ma };
  hipError_t cerr = hipLaunchCooperativeKernel(
      reinterpret_cast<void*>(mega_kernel), dim3(MEGA_GRID), dim3(256), args, 0, stream);

  if (cerr != hipSuccess) {
    // deterministic fallback: proven R10 11-kernel sequence
    (void)hipGetLastError();  // clear sticky error
    conv_kernel<1><<<1280, 256, 0, stream>>>(pk1, b10, b11, record,
                                             (const __bf16*)nullptr, (const __bf16*)nullptr,
                                             (const __bf16*)nullptr, (const __bf16*)nullptr, e1b,
                                             (const float*)nullptr, (float*)nullptr, (float*)nullptr);
    agg_kernel<<<(NN * 64 + 255) / 256, 256, 0, stream>>>(e1b, offs, x21, 64, 32,
                                                          (__bf16*)nullptr, 0, 0);
    nodeproj_kernel<32><<<(NPTILES + 3) / 4, 256, 0, stream>>>(pk2, x21, 32, 64, ur, uc);
    conv_kernel<2><<<1280, 256, 0, stream>>>(pk2, b20, b21, record,
                                             ur, uc, e1b, (const __bf16*)nullptr, e2b,
                                             (const float*)nullptr, (float*)nullptr, (float*)nullptr);
    agg_kernel<<<(NN * 64 + 255) / 256, 256, 0, stream>>>(e2b, offs, x21, 64, 0, x32, 64, 32);
    nodeproj_kernel<64><<<(NPTILES + 3) / 4, 256, 0, stream>>>(pk3, x21, 0, 64, ur, uc);
    conv_kernel<3><<<1280, 256, 0, stream>>>(pk3, b30, b31, record,
                                             ur, uc, e2b, e1b, e3b,
                                             (const float*)nullptr, (float*)nullptr, (float*)nullptr);
    agg_kernel<<<(NN * 64 + 255) / 256, 256, 0, stream>>>(e3b, offs, x32, 64, 0,
                                                          (__bf16*)nullptr, 0, 0);
    nodeproj_kernel<64><<<(NPTILES + 3) / 4, 256, 0, stream>>>(pk4, x32, 0, 64, ur, uc);
    conv_kernel<4><<<1280, 256, 0, stream>>>(pk4, b40, b41, record,
                                             ur, uc, e3b, e2b, (__bf16*)nullptr,
                                             headw, tmpP, tmpEX);
    unpermute_kernel<<<(EE + 255) / 256, 256, 0, stream>>>(inv, tmpP, tmpEX, beta,
                                                           outP, outEX, outB);
  }
}

// Round 14
// 200.628 us; speedup vs baseline: 7.2000x; 7.2000x over previous
//
#include <hip/hip_runtime.h>
#include <hip/hip_bf16.h>

#define EE 400000
#define NN 50000
#define SCAN_NBLK ((NN + 1023) / 1024)     // 49
#define NTILES (EE / 16)          // 25000
#define TPX (NTILES / 8)          // 3125 tiles per XCD chunk
#define NPTILES ((NN + 15) / 16)
#define INIT_NBLK ((NN + 255) / 256)       // 196

typedef float f32x4 __attribute__((ext_vector_type(4)));
typedef __bf16 bf16x8 __attribute__((ext_vector_type(8)));
typedef unsigned int u32;
typedef unsigned int u32x4 __attribute__((ext_vector_type(4)));

static __device__ __forceinline__ bf16x8 u4_as_bf8(u32x4 u) {
  return __builtin_bit_cast(bf16x8, u);
}
static __device__ __forceinline__ u32 relu_pk2(u32 d) {
  u32 m = (d & 0x80008000u) >> 15;
  m ^= 0x00010001u;
  return d & ((m << 16) - m);
}
static __device__ __forceinline__ u32 pk2bf(float a, float b) {
  union { __bf16 h[2]; u32 w; } t;
  t.h[0] = (__bf16)a; t.h[1] = (__bf16)b;
  return t.w;
}

// ---------------- fused: pack all B fragments (blocks 0..42) +
//                  zero counters (blocks 43..) + head biases (block 43) -----
__global__ void init_pack_kernel(const float* __restrict__ w10, const float* __restrict__ w11,
                                 const float* __restrict__ w20, const float* __restrict__ w21,
                                 const float* __restrict__ w30, const float* __restrict__ w31,
                                 const float* __restrict__ w40, const float* __restrict__ w41,
                                 const float* __restrict__ wl01, const float* __restrict__ wl1,
                                 const float* __restrict__ wl02, const float* __restrict__ wl2,
                                 const float* __restrict__ bl01, const float* __restrict__ bl02,
                                 const float* __restrict__ bl1, const float* __restrict__ bl2,
                                 __bf16* __restrict__ pk,
                                 int* __restrict__ count, float* __restrict__ headw) {
  const int t = threadIdx.x;
  if (blockIdx.x >= 43) {
    int i = (blockIdx.x - 43) * 256 + t;
    if (i < NN) count[i] = 0;
    if (blockIdx.x == 43) {
      if (t < 4) {                      // b_ex[c] = bl01@wl1 + bl1
        float s = bl1[t];
        for (int j = 0; j < 32; ++j) s += bl01[j] * wl1[j * 4 + t];
        headw[160 + t] = s;
      } else if (t == 4) {              // b_p = bl02@wl2 + bl2
        float s = bl2[0];
        for (int j = 0; j < 32; ++j) s += bl02[j] * wl2[j];
        headw[164] = s;
      }
    }
    return;
  }
  const int f = blockIdx.x;
  int stage, lf;
  const float *W0, *W1;
  if (f < 4)       { stage = 1; lf = f;      W0 = w10; W1 = w11; }
  else if (f < 14) { stage = 2; lf = f - 4;  W0 = w20; W1 = w21; }
  else if (f < 28) { stage = 3; lf = f - 14; W0 = w30; W1 = w31; }
  else             { stage = 4; lf = f - 28; W0 = w40; W1 = w41; }
#pragma unroll
  for (int u = 0; u < 2; ++u) {
    int idx = t * 2 + u;
    int lane = idx >> 3, i = idx & 7;
    int l15 = lane & 15, g = lane >> 4;
    int k = 8 * g + i;
    float v = 0.f;
    if (stage == 1) {
      if (lf < 2)      v = (k < 4) ? W0[k * 32 + lf * 16 + l15] : 0.f;
      else             v = W1[k * 32 + (lf - 2) * 16 + l15];
    } else if (stage == 2) {
      if (lf < 4)      { int part = lf >> 1, nb = lf & 1; v = W0[(part * 32 + k) * 32 + nb * 16 + l15]; }
      else if (lf < 6) { int nb = lf - 4; v = (k < 4) ? W0[(64 + k) * 32 + nb * 16 + l15] : 0.f; }
      else if (lf < 8) { int nb = lf - 6; v = W0[(68 + k) * 32 + nb * 16 + l15]; }
      else             { int nb = lf - 8; v = W1[k * 32 + nb * 16 + l15]; }
    } else {
      if (lf < 8)       { int part = lf >> 2, kb = (lf >> 1) & 1, nb = lf & 1;
                          v = W0[(part * 64 + kb * 32 + k) * 32 + nb * 16 + l15]; }
      else if (lf < 12) { int eb = (lf - 8) >> 1, nb = lf & 1;
                          v = W0[(128 + eb * 32 + k) * 32 + nb * 16 + l15]; }
      else if (lf < 14) { int nb = lf - 12; v = W1[k * 32 + nb * 16 + l15]; }
      else {
        if (l15 < 4)      { float s = 0.f; for (int j = 0; j < 32; ++j) s += wl01[k * 32 + j] * wl1[j * 4 + l15]; v = s; }
        else if (l15 == 4){ float s = 0.f; for (int j = 0; j < 32; ++j) s += wl02[k * 32 + j] * wl2[j]; v = s; }
      }
    }
    pk[f * 512 + idx] = (__bf16)v;
  }
}

// ---------------- counting sort, GLOBAL row order ----------
__global__ void hist_kernel(const int* __restrict__ rowi, int* __restrict__ count) {
  int e = blockIdx.x * blockDim.x + threadIdx.x;
  if (e < EE) atomicAdd(&count[rowi[e]], 1);
}

__global__ void scanA_kernel(const int* __restrict__ count, int* __restrict__ offs,
                             int* __restrict__ partial) {
  __shared__ int lds[1024];
  const int t = threadIdx.x;
  const int i = blockIdx.x * 1024 + t;
  int v = (i < NN) ? count[i] : 0;
  lds[t] = v;
  __syncthreads();
  for (int off = 1; off < 1024; off <<= 1) {
    int u = (t >= off) ? lds[t - off] : 0;
    __syncthreads();
    lds[t] += u;
    __syncthreads();
  }
  int incl = lds[t];
  if (i < NN) offs[i] = incl - v;
  if (t == 1023) partial[blockIdx.x] = incl;
}

__global__ void scanB_kernel(const int* __restrict__ partial, int* __restrict__ offs,
                             int* __restrict__ cursor) {
  __shared__ int sbase;
  const int t = threadIdx.x;
  const int b = blockIdx.x;
  if (t < 64) {
    int s = 0;
    for (int j = t; j < b; j += 64) s += partial[j];
#pragma unroll
    for (int o = 32; o > 0; o >>= 1) s += __shfl_down(s, o);
    if (t == 0) sbase = s;
  }
  __syncthreads();
  const int base = sbase;
  const int i = b * 1024 + t;
  if (i < NN) {
    int o = offs[i] + base;
    offs[i] = o;
    cursor[i] = o;
  }
  if (b == 0 && t == 0) offs[NN] = EE;
}

// scatter: ONE 16B record per edge into its global sorted position
__global__ void scatter_kernel(const int* __restrict__ rowi, const int* __restrict__ coli,
                               const float* __restrict__ eattr, int* __restrict__ cursor,
                               uint4* __restrict__ record, int* __restrict__ inv) {
  int e = blockIdx.x * blockDim.x + threadIdx.x;
  if (e >= EE) return;
  int r = rowi[e];
  int p = atomicAdd(&cursor[r], 1);
  inv[e] = p;
  const float4 v = *(const float4*)(eattr + (size_t)e * 4);
  uint4 rec;
  rec.x = (u32)r;
  rec.y = (u32)coli[e];
  rec.z = pk2bf(v.x, v.y);
  rec.w = pk2bf(v.z, v.w);
  record[p] = rec;
}

// ---------------- segment mean: edges CONTIGUOUS in [offs[n], offs[n+1]) ----
__global__ void agg_kernel(const __bf16* __restrict__ esrc,
                           const int* __restrict__ offs,
                           __bf16* __restrict__ dst1, int s1, int o1,
                           __bf16* __restrict__ dst2, int s2, int o2) {
  int idx = blockIdx.x * blockDim.x + threadIdx.x;
  int n = idx >> 5;
  int j = idx & 31;
  if (n >= NN) return;
  int a = offs[n], b = offs[n + 1];
  float s = 0.f;
  for (int t = a; t < b; ++t)
    s += (float)esrc[(size_t)t * 32 + j];
  float mean = s / fmaxf((float)(b - a), 1.f);
  __bf16 x = (__bf16)fmaxf(mean, 0.f);
  dst1[(size_t)n * s1 + o1 + j] = x;
  if (dst2) dst2[(size_t)n * s2 + o2 + j] = x;
}

// ---------------- node projection: ur[n] = W_r.x[n], uc[n] = W_c.x[n] ------
template <int NPK>
__launch_bounds__(256, 4)
__global__ void nodeproj_kernel(const __bf16* __restrict__ pk,
                                const __bf16* __restrict__ xcat, int xoff, int xstride,
                                __bf16* __restrict__ ur, __bf16* __restrict__ uc) {
  constexpr int NKB = NPK / 32;
  const int tid = threadIdx.x;
  const int lane = tid & 63;
  const int wid = tid >> 6;
  const int l15 = lane & 15;
  const int g = lane >> 4;

  bf16x8 Br[NKB][2], Bc[NKB][2];
#pragma unroll
  for (int kb = 0; kb < NKB; ++kb)
#pragma unroll
    for (int nb = 0; nb < 2; ++nb) {
      Br[kb][nb] = *(const bf16x8*)(pk + (size_t)((0 * NKB + kb) * 2 + nb) * 512 + lane * 8);
      Bc[kb][nb] = *(const bf16x8*)(pk + (size_t)((1 * NKB + kb) * 2 + nb) * 512 + lane * 8);
    }

  const int t = blockIdx.x * 4 + wid;
  if (t >= NPTILES) return;
  const int base = t * 16;
  const int n = base + l15;
  const int nc = (n < NN) ? n : (NN - 1);

  f32x4 r0 = {0,0,0,0}, r1 = {0,0,0,0}, c0 = {0,0,0,0}, c1 = {0,0,0,0};
#pragma unroll
  for (int kb = 0; kb < NKB; ++kb) {
    bf16x8 a = *(const bf16x8*)(xcat + (size_t)nc * xstride + xoff + kb * 32 + 8 * g);
    r0 = __builtin_amdgcn_mfma_f32_16x16x32_bf16(a, Br[kb][0], r0, 0, 0, 0);
    r1 = __builtin_amdgcn_mfma_f32_16x16x32_bf16(a, Br[kb][1], r1, 0, 0, 0);
    c0 = __builtin_amdgcn_mfma_f32_16x16x32_bf16(a, Bc[kb][0], c0, 0, 0, 0);
    c1 = __builtin_amdgcn_mfma_f32_16x16x32_bf16(a, Bc[kb][1], c1, 0, 0, 0);
  }
#pragma unroll
  for (int r = 0; r < 4; ++r) {
    int m = 4 * g + r;
    if (base + m < NN) {
      size_t row = (size_t)(base + m) * 32;
      ur[row + l15]      = (__bf16)r0[r];
      ur[row + 16 + l15] = (__bf16)r1[r];
      uc[row + l15]      = (__bf16)c0[r];
      uc[row + 16 + l15] = (__bf16)c1[r];
    }
  }
}

// ---------------- fused edge-conv (MFMA), sorted order, XCD-chunked --------
// global sort => XCD chunk [xcd*TPX,(xcd+1)*TPX) is a contiguous rid range.
template <int STAGE>
__launch_bounds__(256, 5)
__global__ void conv_kernel(const __bf16* __restrict__ pk,
                            const float* __restrict__ B0, const float* __restrict__ B1v,
                            const uint4* __restrict__ record,
                            const __bf16* __restrict__ ur,
                            const __bf16* __restrict__ uc,
                            const __bf16* __restrict__ ein1,
                            const __bf16* __restrict__ ein2,
                            __bf16* __restrict__ d1,
                            const float* __restrict__ headw,
                            float* __restrict__ tmpP, float* __restrict__ tmpEX) {
  constexpr int NEB  = (STAGE == 1) ? 1 : 2;
  constexpr int FEB  = (STAGE == 1) ? 0 : (STAGE == 2) ? 4 : 8;
  constexpr int FW1  = (STAGE == 1) ? 2 : (STAGE == 2) ? 8 : 12;
  __shared__ __align__(16) float ldsH[4 * 16 * 36];

  const int tid = threadIdx.x;
  const int lane = tid & 63;
  const int wid = tid >> 6;
  const int l15 = lane & 15;
  const int g = lane >> 4;

  bf16x8 Bf[NEB][2];
#pragma unroll
  for (int eb = 0; eb < NEB; ++eb)
#pragma unroll
    for (int nb = 0; nb < 2; ++nb)
      Bf[eb][nb] = *(const bf16x8*)(pk + (size_t)(FEB + eb * 2 + nb) * 512 + lane * 8);
  bf16x8 B2f[2];
#pragma unroll
  for (int nb = 0; nb < 2; ++nb)
    B2f[nb] = *(const bf16x8*)(pk + (size_t)(FW1 + nb) * 512 + lane * 8);

  bf16x8 I0, I1;
#pragma unroll
  for (int i = 0; i < 8; ++i) {
    int k = 8 * g + i;
    I0[i] = (k == l15)      ? (__bf16)1.0f : (__bf16)0.0f;
    I1[i] = (k == 16 + l15) ? (__bf16)1.0f : (__bf16)0.0f;
  }

  const float b0j0 = B0[l15], b0j1 = B0[l15 + 16];
  const float b1j0 = B1v[l15], b1j1 = B1v[l15 + 16];

  bf16x8 Bh;
  float bexc = 0.f, bp = 0.f;
  if (STAGE == 4) {
    Bh = *(const bf16x8*)(pk + (size_t)14 * 512 + lane * 8);
    if (l15 < 4) bexc = headw[160 + l15];
    bp = headw[164];
  }

  float* hl = &ldsH[wid * 576];

  const int xcd = blockIdx.x & 7;
  const int wloc = (blockIdx.x >> 3) * 4 + wid;
  const int nwl = (gridDim.x >> 3) * 4;
  for (int t0 = wloc; t0 < TPX; t0 += nwl) {
    const int t = xcd * TPX + t0;
    const int base = t * 16;
    const int p = base + l15;

    const uint4 rec = record[p];

    bf16x8 urf, ucf;
    if (STAGE >= 2) {
      int rid = (int)rec.x, cid = (int)rec.y;
      urf = *(const bf16x8*)(ur + (size_t)rid * 32 + 8 * g);
      ucf = *(const bf16x8*)(uc + (size_t)cid * 32 + 8 * g);
    }

    bf16x8 ae;
    if (STAGE <= 2) {
      u32x4 u = {0, 0, 0, 0};
      if (g == 0) { u.x = rec.z; u.y = rec.w; }
      ae = u4_as_bf8(u);
    }

    f32x4 a0a = {0,0,0,0}, a0b = {0,0,0,0}, a1a = {0,0,0,0}, a1b = {0,0,0,0};
    if (STAGE >= 2) {
      a0a = __builtin_amdgcn_mfma_f32_16x16x32_bf16(urf, I0, a0a, 0, 0, 0);
      a1a = __builtin_amdgcn_mfma_f32_16x16x32_bf16(urf, I1, a1a, 0, 0, 0);
      a0a = __builtin_amdgcn_mfma_f32_16x16x32_bf16(ucf, I0, a0a, 0, 0, 0);
      a1a = __builtin_amdgcn_mfma_f32_16x16x32_bf16(ucf, I1, a1a, 0, 0, 0);
    }
#pragma unroll
    for (int eb = 0; eb < NEB; ++eb) {
      bf16x8 a;
      if (STAGE == 1) {
        a = ae;
      } else if (STAGE == 2) {
        if (eb == 0) a = ae;
        else {
          u32x4 u = *(const u32x4*)(ein1 + (size_t)p * 32 + 8 * g);
          u.x = relu_pk2(u.x); u.y = relu_pk2(u.y); u.z = relu_pk2(u.z); u.w = relu_pk2(u.w);
          a = u4_as_bf8(u);
        }
      } else {
        const __bf16* src = (eb == 0) ? ein1 : ein2;
        u32x4 u = *(const u32x4*)(src + (size_t)p * 32 + 8 * g);
        u.x = relu_pk2(u.x); u.y = relu_pk2(u.y); u.z = relu_pk2(u.z); u.w = relu_pk2(u.w);
        a = u4_as_bf8(u);
      }
      a0b = __builtin_amdgcn_mfma_f32_16x16x32_bf16(a, Bf[eb][0], a0b, 0, 0, 0);
      a1b = __builtin_amdgcn_mfma_f32_16x16x32_bf16(a, Bf[eb][1], a1b, 0, 0, 0);
    }
    f32x4 acc0 = a0a + a0b, acc1 = a1a + a1b;

#pragma unroll
    for (int r = 0; r < 4; ++r) {
      int m = 4 * g + r;
      hl[m * 36 + l15]      = fmaxf(acc0[r] + b0j0, 0.f);
      hl[m * 36 + l15 + 16] = fmaxf(acc1[r] + b0j1, 0.f);
    }
    f32x4 h0 = *(const f32x4*)&hl[l15 * 36 + 8 * g];
    f32x4 h1 = *(const f32x4*)&hl[l15 * 36 + 8 * g + 4];
    bf16x8 a2;
#pragma unroll
    for (int i = 0; i < 4; ++i) { a2[i] = (__bf16)h0[i]; a2[i + 4] = (__bf16)h1[i]; }
    f32x4 o0 = {0,0,0,0}, o1 = {0,0,0,0};
    o0 = __builtin_amdgcn_mfma_f32_16x16x32_bf16(a2, B2f[0], o0, 0, 0, 0);
    o1 = __builtin_amdgcn_mfma_f32_16x16x32_bf16(a2, B2f[1], o1, 0, 0, 0);

    if (STAGE <= 3) {
#pragma unroll
      for (int r = 0; r < 4; ++r) {
        int m = 4 * g + r;
        size_t eo = (size_t)(base + m) * 32;
        d1[eo + l15]      = (__bf16)(o0[r] + b1j0);
        d1[eo + l15 + 16] = (__bf16)(o1[r] + b1j1);
      }
    } else {
#pragma unroll
      for (int r = 0; r < 4; ++r) {
        int m = 4 * g + r;
        hl[m * 36 + l15]      = fmaxf(o0[r] + b1j0, 0.f);
        hl[m * 36 + l15 + 16] = fmaxf(o1[r] + b1j1, 0.f);
      }
      f32x4 q0 = *(const f32x4*)&hl[l15 * 36 + 8 * g];
      f32x4 q1 = *(const f32x4*)&hl[l15 * 36 + 8 * g + 4];
      bf16x8 a3;
#pragma unroll
      for (int i = 0; i < 4; ++i) { a3[i] = (__bf16)q0[i]; a3[i + 4] = (__bf16)q1[i]; }
      f32x4 ho = {0,0,0,0};
      ho = __builtin_amdgcn_mfma_f32_16x16x32_bf16(a3, Bh, ho, 0, 0, 0);
#pragma unroll
      for (int r = 0; r < 4; ++r) {
        int m = 4 * g + r;
        int po = base + m;
        float s = ho[r];
        u32 zz = __shfl(rec.z, m);
        u32 ww = __shfl(rec.w, m);
        float v = 0.f, sq = 0.f;
        if (l15 < 4) {
          u32 wzw = (l15 & 2) ? ww : zz;
          u32 bits = (l15 & 1) ? (wzw & 0xffff0000u) : (wzw << 16);
          v = s + bexc + __uint_as_float(bits);
          sq = v * v;
        }
        sq += __shfl_xor(sq, 1);
        sq += __shfl_xor(sq, 2);
        if (l15 < 4) tmpEX[(size_t)po * 4 + l15] = v * (1.f / fmaxf(sqrtf(sq), 1e-12f));
        if (l15 == 4) tmpP[po] = 1.f / (1.f + __expf(-(s + bp)));
      }
    }
  }
}

// ---------------- unpermute outputs + beta copy (fused) ----------------
__global__ void unpermute_kernel(const int* __restrict__ inv,
                                 const float* __restrict__ tmpP,
                                 const float* __restrict__ tmpEX,
                                 const float* __restrict__ beta,
                                 float* __restrict__ outP, float* __restrict__ outEX,
                                 float* __restrict__ outB) {
  int e = blockIdx.x * blockDim.x + threadIdx.x;
  if (e >= EE) return;
  int p = inv[e];
  outP[e] = tmpP[p];
  float4 ex = *(const float4*)(tmpEX + (size_t)p * 4);
  *(float4*)(outEX + (size_t)e * 4) = ex;
  if (e < NN * 3) outB[e] = beta[e];
}

extern "C" void kernel_launch(void* const* d_in, const int* in_sizes, int n_in,
                              void* d_out, int out_size, void* d_ws, size_t ws_size,
                              hipStream_t stream) {
  const float* eattr = (const float*)d_in[2];
  const float* beta = (const float*)d_in[3];
  const float* w10 = (const float*)d_in[4];  const float* b10 = (const float*)d_in[5];
  const float* w11 = (const float*)d_in[6];  const float* b11 = (const float*)d_in[7];
  const float* w20 = (const float*)d_in[8];  const float* b20 = (const float*)d_in[9];
  const float* w21 = (const float*)d_in[10]; const float* b21 = (const float*)d_in[11];
  const float* w30 = (const float*)d_in[12]; const float* b30 = (const float*)d_in[13];
  const float* w31 = (const float*)d_in[14]; const float* b31 = (const float*)d_in[15];
  const float* w40 = (const float*)d_in[16]; const float* b40 = (const float*)d_in[17];
  const float* w41 = (const float*)d_in[18]; const float* b41 = (const float*)d_in[19];
  const float* wl01 = (const float*)d_in[20]; const float* bl01 = (const float*)d_in[21];
  const float* wl02 = (const float*)d_in[22]; const float* bl02 = (const float*)d_in[23];
  const float* wl1 = (const float*)d_in[24];  const float* bl1 = (const float*)d_in[25];
  const float* wl2 = (const float*)d_in[26];  const float* bl2 = (const float*)d_in[27];
  const int* rowi = (const int*)d_in[1];
  const int* coli = rowi + EE;

  char* w = (char*)d_ws;
  auto alloc = [&](size_t bytes) {
    char* p = w;
    w += (bytes + 255) & ~(size_t)255;
    return p;
  };
  __bf16* e1b = (__bf16*)alloc((size_t)EE * 32 * 2);  // pre-relu, sorted order
  __bf16* e2b = (__bf16*)alloc((size_t)EE * 32 * 2);
  __bf16* e3b = (__bf16*)alloc((size_t)EE * 32 * 2);
  __bf16* ur  = (__bf16*)alloc((size_t)NN * 32 * 2);  // node proj, row part
  __bf16* uc  = (__bf16*)alloc((size_t)NN * 32 * 2);  // node proj, col part
  __bf16* x21 = (__bf16*)alloc((size_t)NN * 64 * 2);  // [x2 | x1]
  __bf16* x32 = (__bf16*)alloc((size_t)NN * 64 * 2);  // [x3 | x2]
  int* count = (int*)alloc(NN * 4);
  int* offs = (int*)alloc((NN + 1) * 4);
  int* cursor = (int*)alloc(NN * 4);
  int* inv = (int*)alloc(EE * 4);
  uint4* record = (uint4*)alloc((size_t)EE * 16);     // {rid, cid, ea bf16x4}
  float* tmpP = (float*)alloc((size_t)EE * 4);
  float* tmpEX = (float*)alloc((size_t)EE * 4 * 4);
  float* headw = (float*)alloc(256 * 4);
  int* partial = (int*)alloc(512 * 4);
  __bf16* packw = (__bf16*)alloc((size_t)43 * 512 * 2);

  float* outP = (float*)d_out;
  float* outEX = outP + EE;
  float* outB = outP + (size_t)5 * EE;

  __bf16* pk1 = packw;
  __bf16* pk2 = packw + 4 * 512;
  __bf16* pk3 = packw + 14 * 512;
  __bf16* pk4 = packw + 28 * 512;

  init_pack_kernel<<<43 + INIT_NBLK, 256, 0, stream>>>(
      w10, w11, w20, w21, w30, w31, w40, w41, wl01, wl1, wl02, wl2,
      bl01, bl02, bl1, bl2, packw, count, headw);
  hist_kernel<<<(EE + 255) / 256, 256, 0, stream>>>(rowi, count);
  scanA_kernel<<<SCAN_NBLK, 1024, 0, stream>>>(count, offs, partial);
  scanB_kernel<<<SCAN_NBLK, 1024, 0, stream>>>(partial, offs, cursor);
  scatter_kernel<<<(EE + 255) / 256, 256, 0, stream>>>(rowi, coli, eattr, cursor,
                                                       record, inv);

  conv_kernel<1><<<2048, 256, 0, stream>>>(pk1, b10, b11, record,
                                           (const __bf16*)nullptr, (const __bf16*)nullptr,
                                           (const __bf16*)nullptr, (const __bf16*)nullptr, e1b,
                                           (const float*)nullptr, (float*)nullptr, (float*)nullptr);
  agg_kernel<<<(NN * 32 + 255) / 256, 256, 0, stream>>>(e1b, offs, x21, 64, 32,
                                                        (__bf16*)nullptr, 0, 0);
  nodeproj_kernel<32><<<(NPTILES + 3) / 4, 256, 0, stream>>>(pk2, x21, 32, 64, ur, uc);
  conv_kernel<2><<<2048, 256, 0, stream>>>(pk2, b20, b21, record,
                                           ur, uc, e1b, (const __bf16*)nullptr, e2b,
                                           (const float*)nullptr, (float*)nullptr, (float*)nullptr);
  agg_kernel<<<(NN * 32 + 255) / 256, 256, 0, stream>>>(e2b, offs, x21, 64, 0, x32, 64, 32);
  nodeproj_kernel<64><<<(NPTILES + 3) / 4, 256, 0, stream>>>(pk3, x21, 0, 64, ur, uc);
  conv_kernel<3><<<2048, 256, 0, stream>>>(pk3, b30, b31, record,
                                           ur, uc, e2b, e1b, e3b,
                                           (const float*)nullptr, (float*)nullptr, (float*)nullptr);
  agg_kernel<<<(NN * 32 + 255) / 256, 256, 0, stream>>>(e3b, offs, x32, 64, 0,
                                                        (__bf16*)nullptr, 0, 0);
  nodeproj_kernel<64><<<(NPTILES + 3) / 4, 256, 0, stream>>>(pk4, x32, 0, 64, ur, uc);
  conv_kernel<4><<<2048, 256, 0, stream>>>(pk4, b40, b41, record,
                                           ur, uc, e3b, e2b, (__bf16*)nullptr,
                                           headw, tmpP, tmpEX);
  unpermute_kernel<<<(EE + 255) / 256, 256, 0, stream>>>(inv, tmpP, tmpEX, beta,
                                                         outP, outEX, outB);
}

// Round 15
// 193.105 us; speedup vs baseline: 7.4805x; 1.0390x over previous
//
#include <hip/hip_runtime.h>
#include <hip/hip_bf16.h>

#define EE 400000
#define NN 50000
#define SCAN_NBLK ((NN + 1023) / 1024)     // 49
#define NTILES (EE / 16)          // 25000
#define TPX (NTILES / 8)          // 3125 tiles per XCD chunk
#define NPTILES (NN / 16)         // 3125 (NN % 16 == 0)
#define INIT_NBLK ((NN + 255) / 256)       // 196

typedef float f32x4 __attribute__((ext_vector_type(4)));
typedef __bf16 bf16x8 __attribute__((ext_vector_type(8)));
typedef unsigned int u32;
typedef unsigned int u32x4 __attribute__((ext_vector_type(4)));

static __device__ __forceinline__ bf16x8 u4_as_bf8(u32x4 u) {
  return __builtin_bit_cast(bf16x8, u);
}
static __device__ __forceinline__ u32 relu_pk2(u32 d) {
  u32 m = (d & 0x80008000u) >> 15;
  m ^= 0x00010001u;
  return d & ((m << 16) - m);
}
static __device__ __forceinline__ u32 pk2bf(float a, float b) {
  union { __bf16 h[2]; u32 w; } t;
  t.h[0] = (__bf16)a; t.h[1] = (__bf16)b;
  return t.w;
}

// ---------------- fused: pack all B fragments (blocks 0..42) +
//                  zero counters (blocks 43..) + head biases (block 43) -----
__global__ void init_pack_kernel(const float* __restrict__ w10, const float* __restrict__ w11,
                                 const float* __restrict__ w20, const float* __restrict__ w21,
                                 const float* __restrict__ w30, const float* __restrict__ w31,
                                 const float* __restrict__ w40, const float* __restrict__ w41,
                                 const float* __restrict__ wl01, const float* __restrict__ wl1,
                                 const float* __restrict__ wl02, const float* __restrict__ wl2,
                                 const float* __restrict__ bl01, const float* __restrict__ bl02,
                                 const float* __restrict__ bl1, const float* __restrict__ bl2,
                                 __bf16* __restrict__ pk,
                                 int* __restrict__ count, float* __restrict__ headw) {
  const int t = threadIdx.x;
  if (blockIdx.x >= 43) {
    int i = (blockIdx.x - 43) * 256 + t;
    if (i < NN) count[i] = 0;
    if (blockIdx.x == 43) {
      if (t < 4) {                      // b_ex[c] = bl01@wl1 + bl1
        float s = bl1[t];
        for (int j = 0; j < 32; ++j) s += bl01[j] * wl1[j * 4 + t];
        headw[160 + t] = s;
      } else if (t == 4) {              // b_p = bl02@wl2 + bl2
        float s = bl2[0];
        for (int j = 0; j < 32; ++j) s += bl02[j] * wl2[j];
        headw[164] = s;
      }
    }
    return;
  }
  const int f = blockIdx.x;
  int stage, lf;
  const float *W0, *W1;
  if (f < 4)       { stage = 1; lf = f;      W0 = w10; W1 = w11; }
  else if (f < 14) { stage = 2; lf = f - 4;  W0 = w20; W1 = w21; }
  else if (f < 28) { stage = 3; lf = f - 14; W0 = w30; W1 = w31; }
  else             { stage = 4; lf = f - 28; W0 = w40; W1 = w41; }
#pragma unroll
  for (int u = 0; u < 2; ++u) {
    int idx = t * 2 + u;
    int lane = idx >> 3, i = idx & 7;
    int l15 = lane & 15, g = lane >> 4;
    int k = 8 * g + i;
    float v = 0.f;
    if (stage == 1) {
      if (lf < 2)      v = (k < 4) ? W0[k * 32 + lf * 16 + l15] : 0.f;
      else             v = W1[k * 32 + (lf - 2) * 16 + l15];
    } else if (stage == 2) {
      if (lf < 4)      { int part = lf >> 1, nb = lf & 1; v = W0[(part * 32 + k) * 32 + nb * 16 + l15]; }
      else if (lf < 6) { int nb = lf - 4; v = (k < 4) ? W0[(64 + k) * 32 + nb * 16 + l15] : 0.f; }
      else if (lf < 8) { int nb = lf - 6; v = W0[(68 + k) * 32 + nb * 16 + l15]; }
      else             { int nb = lf - 8; v = W1[k * 32 + nb * 16 + l15]; }
    } else {
      if (lf < 8)       { int part = lf >> 2, kb = (lf >> 1) & 1, nb = lf & 1;
                          v = W0[(part * 64 + kb * 32 + k) * 32 + nb * 16 + l15]; }
      else if (lf < 12) { int eb = (lf - 8) >> 1, nb = lf & 1;
                          v = W0[(128 + eb * 32 + k) * 32 + nb * 16 + l15]; }
      else if (lf < 14) { int nb = lf - 12; v = W1[k * 32 + nb * 16 + l15]; }
      else {
        if (l15 < 4)      { float s = 0.f; for (int j = 0; j < 32; ++j) s += wl01[k * 32 + j] * wl1[j * 4 + l15]; v = s; }
        else if (l15 == 4){ float s = 0.f; for (int j = 0; j < 32; ++j) s += wl02[k * 32 + j] * wl2[j]; v = s; }
      }
    }
    pk[f * 512 + idx] = (__bf16)v;
  }
}

// ---------------- counting sort, GLOBAL row order ----------
__global__ void hist_kernel(const int* __restrict__ rowi, int* __restrict__ count) {
  int e = blockIdx.x * blockDim.x + threadIdx.x;
  if (e < EE) atomicAdd(&count[rowi[e]], 1);
}

__global__ void scanA_kernel(const int* __restrict__ count, int* __restrict__ offs,
                             int* __restrict__ partial) {
  __shared__ int lds[1024];
  const int t = threadIdx.x;
  const int i = blockIdx.x * 1024 + t;
  int v = (i < NN) ? count[i] : 0;
  lds[t] = v;
  __syncthreads();
  for (int off = 1; off < 1024; off <<= 1) {
    int u = (t >= off) ? lds[t - off] : 0;
    __syncthreads();
    lds[t] += u;
    __syncthreads();
  }
  int incl = lds[t];
  if (i < NN) offs[i] = incl - v;
  if (t == 1023) partial[blockIdx.x] = incl;
}

__global__ void scanB_kernel(const int* __restrict__ partial, int* __restrict__ offs,
                             int* __restrict__ cursor) {
  __shared__ int sbase;
  const int t = threadIdx.x;
  const int b = blockIdx.x;
  if (t < 64) {
    int s = 0;
    for (int j = t; j < b; j += 64) s += partial[j];
#pragma unroll
    for (int o = 32; o > 0; o >>= 1) s += __shfl_down(s, o);
    if (t == 0) sbase = s;
  }
  __syncthreads();
  const int base = sbase;
  const int i = b * 1024 + t;
  if (i < NN) {
    int o = offs[i] + base;
    offs[i] = o;
    cursor[i] = o;
  }
  if (b == 0 && t == 0) offs[NN] = EE;
}

// scatter: ONE 16B record per edge into its global sorted position
__global__ void scatter_kernel(const int* __restrict__ rowi, const int* __restrict__ coli,
                               const float* __restrict__ eattr, int* __restrict__ cursor,
                               uint4* __restrict__ record, int* __restrict__ inv) {
  int e = blockIdx.x * blockDim.x + threadIdx.x;
  if (e >= EE) return;
  int r = rowi[e];
  int p = atomicAdd(&cursor[r], 1);
  inv[e] = p;
  const float4 v = *(const float4*)(eattr + (size_t)e * 4);
  uint4 rec;
  rec.x = (u32)r;
  rec.y = (u32)coli[e];
  rec.z = pk2bf(v.x, v.y);
  rec.w = pk2bf(v.z, v.w);
  record[p] = rec;
}

// ---------------- fused segment-mean + node projection ---------------------
// Per block: 16 nodes. Phase 1 (all 4 waves): mean of contiguous edge
// segment -> relu -> LDS [16][36] (padded, conv's transpose pattern) and
// fresh x-buf. Phase 2 (waves 0,1): MFMA projection; wave0 -> ur (W_r part),
// wave1 -> uc (W_c part). kb==0 A-frag from LDS (fresh), kb==1 from xold.
template <int NKB>
__launch_bounds__(256, 4)
__global__ void aggproj_kernel(const __bf16* __restrict__ esrc,
                               const int* __restrict__ offs,
                               const __bf16* __restrict__ pk,
                               const __bf16* __restrict__ xold,
                               __bf16* __restrict__ xfresh,
                               __bf16* __restrict__ ur, __bf16* __restrict__ uc) {
  __shared__ __align__(16) float hl[16 * 36];
  const int t = threadIdx.x;
  const int base = blockIdx.x * 16;

#pragma unroll
  for (int q = 0; q < 2; ++q) {
    int idx = q * 256 + t;
    int nl = idx >> 5, j = idx & 31;
    int n = base + nl;
    int a = offs[n], b = offs[n + 1];
    float s = 0.f;
    for (int e = a; e < b; ++e)
      s += (float)esrc[(size_t)e * 32 + j];
    float x = fmaxf(s / fmaxf((float)(b - a), 1.f), 0.f);
    hl[nl * 36 + j] = x;
    xfresh[(size_t)n * 32 + j] = (__bf16)x;
  }
  __syncthreads();

  const int lane = t & 63;
  const int wid = t >> 6;
  if (wid >= 2) return;
  const int l15 = lane & 15;
  const int g = lane >> 4;

  f32x4 o0 = {0, 0, 0, 0}, o1 = {0, 0, 0, 0};
#pragma unroll
  for (int kb = 0; kb < NKB; ++kb) {
    bf16x8 Bf0 = *(const bf16x8*)(pk + (size_t)((wid * NKB + kb) * 2 + 0) * 512 + lane * 8);
    bf16x8 Bf1 = *(const bf16x8*)(pk + (size_t)((wid * NKB + kb) * 2 + 1) * 512 + lane * 8);
    bf16x8 a;
    if (kb == 0) {
      f32x4 h0 = *(const f32x4*)&hl[l15 * 36 + 8 * g];
      f32x4 h1 = *(const f32x4*)&hl[l15 * 36 + 8 * g + 4];
#pragma unroll
      for (int i = 0; i < 4; ++i) { a[i] = (__bf16)h0[i]; a[i + 4] = (__bf16)h1[i]; }
    } else {
      a = *(const bf16x8*)(xold + (size_t)(base + l15) * 32 + 8 * g);
    }
    o0 = __builtin_amdgcn_mfma_f32_16x16x32_bf16(a, Bf0, o0, 0, 0, 0);
    o1 = __builtin_amdgcn_mfma_f32_16x16x32_bf16(a, Bf1, o1, 0, 0, 0);
  }
  __bf16* dst = (wid == 0) ? ur : uc;
#pragma unroll
  for (int r = 0; r < 4; ++r) {
    int m = 4 * g + r;
    size_t row = (size_t)(base + m) * 32;
    dst[row + l15]      = (__bf16)o0[r];
    dst[row + 16 + l15] = (__bf16)o1[r];
  }
}

// ---------------- fused edge-conv (MFMA), sorted order, XCD-chunked --------
template <int STAGE>
__launch_bounds__(256, 5)
__global__ void conv_kernel(const __bf16* __restrict__ pk,
                            const float* __restrict__ B0, const float* __restrict__ B1v,
                            const uint4* __restrict__ record,
                            const __bf16* __restrict__ ur,
                            const __bf16* __restrict__ uc,
                            const __bf16* __restrict__ ein1,
                            const __bf16* __restrict__ ein2,
                            __bf16* __restrict__ d1,
                            const float* __restrict__ headw,
                            float* __restrict__ tmpP, float* __restrict__ tmpEX) {
  constexpr int NEB  = (STAGE == 1) ? 1 : 2;
  constexpr int FEB  = (STAGE == 1) ? 0 : (STAGE == 2) ? 4 : 8;
  constexpr int FW1  = (STAGE == 1) ? 2 : (STAGE == 2) ? 8 : 12;
  __shared__ __align__(16) float ldsH[4 * 16 * 36];

  const int tid = threadIdx.x;
  const int lane = tid & 63;
  const int wid = tid >> 6;
  const int l15 = lane & 15;
  const int g = lane >> 4;

  bf16x8 Bf[NEB][2];
#pragma unroll
  for (int eb = 0; eb < NEB; ++eb)
#pragma unroll
    for (int nb = 0; nb < 2; ++nb)
      Bf[eb][nb] = *(const bf16x8*)(pk + (size_t)(FEB + eb * 2 + nb) * 512 + lane * 8);
  bf16x8 B2f[2];
#pragma unroll
  for (int nb = 0; nb < 2; ++nb)
    B2f[nb] = *(const bf16x8*)(pk + (size_t)(FW1 + nb) * 512 + lane * 8);

  bf16x8 I0, I1;
#pragma unroll
  for (int i = 0; i < 8; ++i) {
    int k = 8 * g + i;
    I0[i] = (k == l15)      ? (__bf16)1.0f : (__bf16)0.0f;
    I1[i] = (k == 16 + l15) ? (__bf16)1.0f : (__bf16)0.0f;
  }

  const float b0j0 = B0[l15], b0j1 = B0[l15 + 16];
  const float b1j0 = B1v[l15], b1j1 = B1v[l15 + 16];

  bf16x8 Bh;
  float bexc = 0.f, bp = 0.f;
  if (STAGE == 4) {
    Bh = *(const bf16x8*)(pk + (size_t)14 * 512 + lane * 8);
    if (l15 < 4) bexc = headw[160 + l15];
    bp = headw[164];
  }

  float* hl = &ldsH[wid * 576];

  const int xcd = blockIdx.x & 7;
  const int wloc = (blockIdx.x >> 3) * 4 + wid;
  const int nwl = (gridDim.x >> 3) * 4;
  for (int t0 = wloc; t0 < TPX; t0 += nwl) {
    const int t = xcd * TPX + t0;
    const int base = t * 16;
    const int p = base + l15;

    const uint4 rec = record[p];

    bf16x8 urf, ucf;
    if (STAGE >= 2) {
      int rid = (int)rec.x, cid = (int)rec.y;
      urf = *(const bf16x8*)(ur + (size_t)rid * 32 + 8 * g);
      ucf = *(const bf16x8*)(uc + (size_t)cid * 32 + 8 * g);
    }

    bf16x8 ae;
    if (STAGE <= 2) {
      u32x4 u = {0, 0, 0, 0};
      if (g == 0) { u.x = rec.z; u.y = rec.w; }
      ae = u4_as_bf8(u);
    }

    f32x4 a0a = {0,0,0,0}, a0b = {0,0,0,0}, a1a = {0,0,0,0}, a1b = {0,0,0,0};
    if (STAGE >= 2) {
      a0a = __builtin_amdgcn_mfma_f32_16x16x32_bf16(urf, I0, a0a, 0, 0, 0);
      a1a = __builtin_amdgcn_mfma_f32_16x16x32_bf16(urf, I1, a1a, 0, 0, 0);
      a0a = __builtin_amdgcn_mfma_f32_16x16x32_bf16(ucf, I0, a0a, 0, 0, 0);
      a1a = __builtin_amdgcn_mfma_f32_16x16x32_bf16(ucf, I1, a1a, 0, 0, 0);
    }
#pragma unroll
    for (int eb = 0; eb < NEB; ++eb) {
      bf16x8 a;
      if (STAGE == 1) {
        a = ae;
      } else if (STAGE == 2) {
        if (eb == 0) a = ae;
        else {
          u32x4 u = *(const u32x4*)(ein1 + (size_t)p * 32 + 8 * g);
          u.x = relu_pk2(u.x); u.y = relu_pk2(u.y); u.z = relu_pk2(u.z); u.w = relu_pk2(u.w);
          a = u4_as_bf8(u);
        }
      } else {
        const __bf16* src = (eb == 0) ? ein1 : ein2;
        u32x4 u = *(const u32x4*)(src + (size_t)p * 32 + 8 * g);
        u.x = relu_pk2(u.x); u.y = relu_pk2(u.y); u.z = relu_pk2(u.z); u.w = relu_pk2(u.w);
        a = u4_as_bf8(u);
      }
      a0b = __builtin_amdgcn_mfma_f32_16x16x32_bf16(a, Bf[eb][0], a0b, 0, 0, 0);
      a1b = __builtin_amdgcn_mfma_f32_16x16x32_bf16(a, Bf[eb][1], a1b, 0, 0, 0);
    }
    f32x4 acc0 = a0a + a0b, acc1 = a1a + a1b;

#pragma unroll
    for (int r = 0; r < 4; ++r) {
      int m = 4 * g + r;
      hl[m * 36 + l15]      = fmaxf(acc0[r] + b0j0, 0.f);
      hl[m * 36 + l15 + 16] = fmaxf(acc1[r] + b0j1, 0.f);
    }
    f32x4 h0 = *(const f32x4*)&hl[l15 * 36 + 8 * g];
    f32x4 h1 = *(const f32x4*)&hl[l15 * 36 + 8 * g + 4];
    bf16x8 a2;
#pragma unroll
    for (int i = 0; i < 4; ++i) { a2[i] = (__bf16)h0[i]; a2[i + 4] = (__bf16)h1[i]; }
    f32x4 o0 = {0,0,0,0}, o1 = {0,0,0,0};
    o0 = __builtin_amdgcn_mfma_f32_16x16x32_bf16(a2, B2f[0], o0, 0, 0, 0);
    o1 = __builtin_amdgcn_mfma_f32_16x16x32_bf16(a2, B2f[1], o1, 0, 0, 0);

    if (STAGE <= 3) {
#pragma unroll
      for (int r = 0; r < 4; ++r) {
        int m = 4 * g + r;
        size_t eo = (size_t)(base + m) * 32;
        d1[eo + l15]      = (__bf16)(o0[r] + b1j0);
        d1[eo + l15 + 16] = (__bf16)(o1[r] + b1j1);
      }
    } else {
#pragma unroll
      for (int r = 0; r < 4; ++r) {
        int m = 4 * g + r;
        hl[m * 36 + l15]      = fmaxf(o0[r] + b1j0, 0.f);
        hl[m * 36 + l15 + 16] = fmaxf(o1[r] + b1j1, 0.f);
      }
      f32x4 q0 = *(const f32x4*)&hl[l15 * 36 + 8 * g];
      f32x4 q1 = *(const f32x4*)&hl[l15 * 36 + 8 * g + 4];
      bf16x8 a3;
#pragma unroll
      for (int i = 0; i < 4; ++i) { a3[i] = (__bf16)q0[i]; a3[i + 4] = (__bf16)q1[i]; }
      f32x4 ho = {0,0,0,0};
      ho = __builtin_amdgcn_mfma_f32_16x16x32_bf16(a3, Bh, ho, 0, 0, 0);
#pragma unroll
      for (int r = 0; r < 4; ++r) {
        int m = 4 * g + r;
        int po = base + m;
        float s = ho[r];
        u32 zz = __shfl(rec.z, m);
        u32 ww = __shfl(rec.w, m);
        float v = 0.f, sq = 0.f;
        if (l15 < 4) {
          u32 wzw = (l15 & 2) ? ww : zz;
          u32 bits = (l15 & 1) ? (wzw & 0xffff0000u) : (wzw << 16);
          v = s + bexc + __uint_as_float(bits);
          sq = v * v;
        }
        sq += __shfl_xor(sq, 1);
        sq += __shfl_xor(sq, 2);
        if (l15 < 4) tmpEX[(size_t)po * 4 + l15] = v * (1.f / fmaxf(sqrtf(sq), 1e-12f));
        if (l15 == 4) tmpP[po] = 1.f / (1.f + __expf(-(s + bp)));
      }
    }
  }
}

// ---------------- unpermute outputs + beta copy (fused) ----------------
__global__ void unpermute_kernel(const int* __restrict__ inv,
                                 const float* __restrict__ tmpP,
                                 const float* __restrict__ tmpEX,
                                 const float* __restrict__ beta,
                                 float* __restrict__ outP, float* __restrict__ outEX,
                                 float* __restrict__ outB) {
  int e = blockIdx.x * blockDim.x + threadIdx.x;
  if (e >= EE) return;
  int p = inv[e];
  outP[e] = tmpP[p];
  float4 ex = *(const float4*)(tmpEX + (size_t)p * 4);
  *(float4*)(outEX + (size_t)e * 4) = ex;
  if (e < NN * 3) outB[e] = beta[e];
}

extern "C" void kernel_launch(void* const* d_in, const int* in_sizes, int n_in,
                              void* d_out, int out_size, void* d_ws, size_t ws_size,
                              hipStream_t stream) {
  const float* eattr = (const float*)d_in[2];
  const float* beta = (const float*)d_in[3];
  const float* w10 = (const float*)d_in[4];  const float* b10 = (const float*)d_in[5];
  const float* w11 = (const float*)d_in[6];  const float* b11 = (const float*)d_in[7];
  const float* w20 = (const float*)d_in[8];  const float* b20 = (const float*)d_in[9];
  const float* w21 = (const float*)d_in[10]; const float* b21 = (const float*)d_in[11];
  const float* w30 = (const float*)d_in[12]; const float* b30 = (const float*)d_in[13];
  const float* w31 = (const float*)d_in[14]; const float* b31 = (const float*)d_in[15];
  const float* w40 = (const float*)d_in[16]; const float* b40 = (const float*)d_in[17];
  const float* w41 = (const float*)d_in[18]; const float* b41 = (const float*)d_in[19];
  const float* wl01 = (const float*)d_in[20]; const float* bl01 = (const float*)d_in[21];
  const float* wl02 = (const float*)d_in[22]; const float* bl02 = (const float*)d_in[23];
  const float* wl1 = (const float*)d_in[24];  const float* bl1 = (const float*)d_in[25];
  const float* wl2 = (const float*)d_in[26];  const float* bl2 = (const float*)d_in[27];
  const int* rowi = (const int*)d_in[1];
  const int* coli = rowi + EE;

  char* w = (char*)d_ws;
  auto alloc = [&](size_t bytes) {
    char* p = w;
    w += (bytes + 255) & ~(size_t)255;
    return p;
  };
  __bf16* e1b = (__bf16*)alloc((size_t)EE * 32 * 2);  // pre-relu, sorted order
  __bf16* e2b = (__bf16*)alloc((size_t)EE * 32 * 2);
  __bf16* e3b = (__bf16*)alloc((size_t)EE * 32 * 2);
  __bf16* ur  = (__bf16*)alloc((size_t)NN * 32 * 2);  // node proj, row part
  __bf16* uc  = (__bf16*)alloc((size_t)NN * 32 * 2);  // node proj, col part
  __bf16* x1b = (__bf16*)alloc((size_t)NN * 32 * 2);
  __bf16* x2b = (__bf16*)alloc((size_t)NN * 32 * 2);
  __bf16* x3b = (__bf16*)alloc((size_t)NN * 32 * 2);
  int* count = (int*)alloc(NN * 4);
  int* offs = (int*)alloc((NN + 1) * 4);
  int* cursor = (int*)alloc(NN * 4);
  int* inv = (int*)alloc(EE * 4);
  uint4* record = (uint4*)alloc((size_t)EE * 16);     // {rid, cid, ea bf16x4}
  float* tmpP = (float*)alloc((size_t)EE * 4);
  float* tmpEX = (float*)alloc((size_t)EE * 4 * 4);
  float* headw = (float*)alloc(256 * 4);
  int* partial = (int*)alloc(512 * 4);
  __bf16* packw = (__bf16*)alloc((size_t)43 * 512 * 2);

  float* outP = (float*)d_out;
  float* outEX = outP + EE;
  float* outB = outP + (size_t)5 * EE;

  __bf16* pk1 = packw;
  __bf16* pk2 = packw + 4 * 512;
  __bf16* pk3 = packw + 14 * 512;
  __bf16* pk4 = packw + 28 * 512;

  init_pack_kernel<<<43 + INIT_NBLK, 256, 0, stream>>>(
      w10, w11, w20, w21, w30, w31, w40, w41, wl01, wl1, wl02, wl2,
      bl01, bl02, bl1, bl2, packw, count, headw);
  hist_kernel<<<(EE + 255) / 256, 256, 0, stream>>>(rowi, count);
  scanA_kernel<<<SCAN_NBLK, 1024, 0, stream>>>(count, offs, partial);
  scanB_kernel<<<SCAN_NBLK, 1024, 0, stream>>>(partial, offs, cursor);
  scatter_kernel<<<(EE + 255) / 256, 256, 0, stream>>>(rowi, coli, eattr, cursor,
                                                       record, inv);

  conv_kernel<1><<<2048, 256, 0, stream>>>(pk1, b10, b11, record,
                                           (const __bf16*)nullptr, (const __bf16*)nullptr,
                                           (const __bf16*)nullptr, (const __bf16*)nullptr, e1b,
                                           (const float*)nullptr, (float*)nullptr, (float*)nullptr);
  aggproj_kernel<1><<<NPTILES, 256, 0, stream>>>(e1b, offs, pk2,
                                                 (const __bf16*)nullptr, x1b, ur, uc);
  conv_kernel<2><<<2048, 256, 0, stream>>>(pk2, b20, b21, record,
                                           ur, uc, e1b, (const __bf16*)nullptr, e2b,
                                           (const float*)nullptr, (float*)nullptr, (float*)nullptr);
  aggproj_kernel<2><<<NPTILES, 256, 0, stream>>>(e2b, offs, pk3, x1b, x2b, ur, uc);
  conv_kernel<3><<<2048, 256, 0, stream>>>(pk3, b30, b31, record,
                                           ur, uc, e2b, e1b, e3b,
                                           (const float*)nullptr, (float*)nullptr, (float*)nullptr);
  aggproj_kernel<2><<<NPTILES, 256, 0, stream>>>(e3b, offs, pk4, x2b, x3b, ur, uc);
  conv_kernel<4><<<2048, 256, 0, stream>>>(pk4, b40, b41, record,
                                           ur, uc, e3b, e2b, (__bf16*)nullptr,
                                           headw, tmpP, tmpEX);
  unpermute_kernel<<<(EE + 255) / 256, 256, 0, stream>>>(inv, tmpP, tmpEX, beta,
                                                         outP, outEX, outB);
}